// Round 2
// baseline (242.514 us; speedup 1.0000x reference)
//
#include <hip/hip_runtime.h>
#include <hip/hip_bf16.h>

typedef __attribute__((ext_vector_type(8))) short bf16x8;
typedef __attribute__((ext_vector_type(4))) short bf16x4;
typedef __attribute__((ext_vector_type(4))) float f32x4;

constexpr int NT   = 512;   // tiles
constexpr int NP   = 512;   // points (M)
constexpr int DIN  = 256;   // K
constexpr int DOUT = 256;   // N

constexpr int BM = 128, BN = 128, BK = 64;

__device__ __forceinline__ short f2bf(float f) {
  __hip_bfloat16 h = __float2bfloat16(f);
  return __builtin_bit_cast(short, h);
}

// element index into a [rows][BK] bf16 LDS tile, XOR-swizzled per row.
// k must be a multiple of 4 (writes) or 8 (b128 reads); swizzle bits are
// multiples of 8 elements (16B granules), so vector contiguity is preserved.
__device__ __forceinline__ int swz(int r, int k) {
  return r * BK + (k ^ (((r ^ (r >> 3)) & 7) << 3));
}

__global__ __launch_bounds__(256, 2) void adaptive_linear_mfma(
    const float* __restrict__ x,     // [NT][NP][DIN]
    const int*   __restrict__ idx,   // [NT]
    const float* __restrict__ w,     // [CH][DIN][DOUT]
    const float* __restrict__ bias,  // [DOUT]
    float*       __restrict__ out)   // [NT][NP][DOUT]
{
  __shared__ short As[BM * BK];  // x tile,  [m][k]   swizzled
  __shared__ short Bs[BN * BK];  // W tile,  [n][k]   (transposed), swizzled

  const int tid = threadIdx.x;
  const int bid = blockIdx.x;
  const int t   = bid >> 3;          // 8 blocks per tile (4 m-tiles x 2 n-tiles)
  const int mt  = (bid >> 1) & 3;
  const int ntile = bid & 1;

  const int c = idx[t];
  const float* xb = x + (size_t)t * NP * DIN + (size_t)mt * BM * DIN;
  const float* wb = w + (size_t)c * DIN * DOUT + ntile * BN;
  float*       ob = out + (size_t)t * NP * DOUT + (size_t)mt * BM * DOUT + ntile * BN;

  const int l    = tid & 63;
  const int wid  = tid >> 6;        // 4 waves: 2x2
  const int wm   = wid >> 1;
  const int wn   = wid & 1;
  const int lrow = l & 15;          // fragment row/col lane index
  const int lk   = l >> 4;          // k-chunk selector (0..3)

  f32x4 acc[4][4] = {};

  for (int kt = 0; kt < DIN / BK; ++kt) {
    // ---- stage A: As[m][k] = bf16(xb[m][kt*BK + k]), 128x64
    {
      const float* src = xb + kt * BK;
      const int k4 = (tid & 15) * 4;
      const int m0 = tid >> 4;
      #pragma unroll
      for (int i = 0; i < 8; ++i) {
        const int m = m0 + i * 16;
        const float4 v = *reinterpret_cast<const float4*>(src + (size_t)m * DIN + k4);
        bf16x4 h = { f2bf(v.x), f2bf(v.y), f2bf(v.z), f2bf(v.w) };
        *reinterpret_cast<bf16x4*>(&As[swz(m, k4)]) = h;
      }
    }
    // ---- stage B (transposed): Bs[n][k] = bf16(wb[(kt*BK+k)*DOUT + n]), 64x128 -> [128][64]
    {
      const float* src = wb + (size_t)(kt * BK) * DOUT;
      const int n4 = (tid & 31) * 4;
      const int kb = (tid >> 5) * 4;
      #pragma unroll
      for (int p = 0; p < 2; ++p) {
        const int kloc = p * 32 + kb;
        const float4 v0 = *reinterpret_cast<const float4*>(src + (size_t)(kloc + 0) * DOUT + n4);
        const float4 v1 = *reinterpret_cast<const float4*>(src + (size_t)(kloc + 1) * DOUT + n4);
        const float4 v2 = *reinterpret_cast<const float4*>(src + (size_t)(kloc + 2) * DOUT + n4);
        const float4 v3 = *reinterpret_cast<const float4*>(src + (size_t)(kloc + 3) * DOUT + n4);
        // in-register 4x4 transpose, K-contiguous b64 writes
        bf16x4 h0 = { f2bf(v0.x), f2bf(v1.x), f2bf(v2.x), f2bf(v3.x) };
        bf16x4 h1 = { f2bf(v0.y), f2bf(v1.y), f2bf(v2.y), f2bf(v3.y) };
        bf16x4 h2 = { f2bf(v0.z), f2bf(v1.z), f2bf(v2.z), f2bf(v3.z) };
        bf16x4 h3 = { f2bf(v0.w), f2bf(v1.w), f2bf(v2.w), f2bf(v3.w) };
        *reinterpret_cast<bf16x4*>(&Bs[swz(n4 + 0, kloc)]) = h0;
        *reinterpret_cast<bf16x4*>(&Bs[swz(n4 + 1, kloc)]) = h1;
        *reinterpret_cast<bf16x4*>(&Bs[swz(n4 + 2, kloc)]) = h2;
        *reinterpret_cast<bf16x4*>(&Bs[swz(n4 + 3, kloc)]) = h3;
      }
    }
    __syncthreads();

    // ---- compute: 2 k-chunks of 32, 4x4 fragments of 16x16
    #pragma unroll
    for (int kc = 0; kc < 2; ++kc) {
      const int ke = kc * 32 + lk * 8;
      bf16x8 a[4], b[4];
      #pragma unroll
      for (int fm = 0; fm < 4; ++fm) {
        const int r = wm * 64 + fm * 16 + lrow;
        a[fm] = *reinterpret_cast<const bf16x8*>(&As[swz(r, ke)]);
      }
      #pragma unroll
      for (int fn = 0; fn < 4; ++fn) {
        const int n = wn * 64 + fn * 16 + lrow;
        b[fn] = *reinterpret_cast<const bf16x8*>(&Bs[swz(n, ke)]);
      }
      #pragma unroll
      for (int fm = 0; fm < 4; ++fm)
        #pragma unroll
        for (int fn = 0; fn < 4; ++fn)
          acc[fm][fn] = __builtin_amdgcn_mfma_f32_16x16x32_bf16(
              a[fm], b[fn], acc[fm][fn], 0, 0, 0);
    }
    __syncthreads();
  }

  // ---- epilogue: add bias, store f32
  float bv[4];
  #pragma unroll
  for (int fn = 0; fn < 4; ++fn)
    bv[fn] = bias[ntile * BN + wn * 64 + fn * 16 + lrow];

  #pragma unroll
  for (int fm = 0; fm < 4; ++fm) {
    const int r0 = wm * 64 + fm * 16 + lk * 4;
    #pragma unroll
    for (int fn = 0; fn < 4; ++fn) {
      const int col = wn * 64 + fn * 16 + lrow;
      #pragma unroll
      for (int rr = 0; rr < 4; ++rr) {
        ob[(size_t)(r0 + rr) * DOUT + col] = acc[fm][fn][rr] + bv[fn];
      }
    }
  }
}

extern "C" void kernel_launch(void* const* d_in, const int* in_sizes, int n_in,
                              void* d_out, int out_size, void* d_ws, size_t ws_size,
                              hipStream_t stream) {
  const float* x    = (const float*)d_in[0];
  const int*   idx  = (const int*)d_in[1];
  const float* w    = (const float*)d_in[2];
  const float* bias = (const float*)d_in[3];
  float* out = (float*)d_out;

  const int grid = NT * (NP / BM) * (DOUT / BN);  // 512*4*2 = 4096
  adaptive_linear_mfma<<<grid, 256, 0, stream>>>(x, idx, w, bias, out);
}

// Round 4
// 219.043 us; speedup vs baseline: 1.1072x; 1.1072x over previous
//
#include <hip/hip_runtime.h>
#include <hip/hip_bf16.h>

typedef __attribute__((ext_vector_type(8))) short bf16x8;
typedef __attribute__((ext_vector_type(4))) short bf16x4;
typedef __attribute__((ext_vector_type(4))) float f32x4;

constexpr int NT   = 512;   // tiles
constexpr int NP   = 512;   // points (M)
constexpr int DIN  = 256;   // K
constexpr int DOUT = 256;   // N

__device__ __forceinline__ short f2bf(float f) {
  __hip_bfloat16 h = __float2bfloat16(f);
  return __builtin_bit_cast(short, h);
}

__device__ __forceinline__ bf16x8 cvt8(float4 a, float4 b) {
  bf16x8 r;
  r[0] = f2bf(a.x); r[1] = f2bf(a.y); r[2] = f2bf(a.z); r[3] = f2bf(a.w);
  r[4] = f2bf(b.x); r[5] = f2bf(b.y); r[6] = f2bf(b.z); r[7] = f2bf(b.w);
  return r;
}

// Ws is [n][k] bf16 (K-contiguous per row), 256x256 = 128 KB.
// XOR-swizzle k in 8-element (16 B) granules by (n&7) so that the b-fragment
// ds_read_b128 (lanes 0..15 at consecutive n, same k) spreads across banks.
__device__ __forceinline__ int wswz(int n, int k) {
  return n * DIN + (k ^ ((n & 7) << 3));
}

__global__ __launch_bounds__(512, 2) void adaptive_linear_ws(
    const float* __restrict__ x,     // [NT][NP][DIN]
    const int*   __restrict__ idx,   // [NT]
    const float* __restrict__ w,     // [CH][DIN][DOUT]
    const float* __restrict__ bias,  // [DOUT]
    float*       __restrict__ out)   // [NT][NP][DOUT]
{
  __shared__ short Ws[DOUT * DIN];   // transposed weight channel, bf16, 128 KB

  const int tid = threadIdx.x;
  const int t   = blockIdx.x;

  const int c = idx[t];
  const float* xb = x   + (size_t)t * NP * DIN;
  const float* wb = w   + (size_t)c * DIN * DOUT;
  float*       ob = out + (size_t)t * NP * DOUT;

  // ---- stage W[c] (f32 [K][N]) -> Ws (bf16 [N][K], swizzled), once per block
  // decomposition: kgroup = tid&7 spreads k across adjacent lanes so the
  // transpose ds_write_b64s cover many banks; nidx = tid>>3 covers n.
  {
    const int kgroup = tid & 7;        // k sub-offset within a 32-k slab
    const int nidx   = tid >> 3;       // 0..63 -> n4 = nidx*4
    const int n4     = nidx * 4;
    #pragma unroll
    for (int kk = 0; kk < 8; ++kk) {
      const int k0 = kk * 32 + kgroup * 4;
      const float* src = wb + (size_t)k0 * DOUT + n4;
      const float4 v0 = *reinterpret_cast<const float4*>(src + 0 * DOUT);
      const float4 v1 = *reinterpret_cast<const float4*>(src + 1 * DOUT);
      const float4 v2 = *reinterpret_cast<const float4*>(src + 2 * DOUT);
      const float4 v3 = *reinterpret_cast<const float4*>(src + 3 * DOUT);
      bf16x4 h0 = { f2bf(v0.x), f2bf(v1.x), f2bf(v2.x), f2bf(v3.x) };
      bf16x4 h1 = { f2bf(v0.y), f2bf(v1.y), f2bf(v2.y), f2bf(v3.y) };
      bf16x4 h2 = { f2bf(v0.z), f2bf(v1.z), f2bf(v2.z), f2bf(v3.z) };
      bf16x4 h3 = { f2bf(v0.w), f2bf(v1.w), f2bf(v2.w), f2bf(v3.w) };
      *reinterpret_cast<bf16x4*>(&Ws[wswz(n4 + 0, k0)]) = h0;
      *reinterpret_cast<bf16x4*>(&Ws[wswz(n4 + 1, k0)]) = h1;
      *reinterpret_cast<bf16x4*>(&Ws[wswz(n4 + 2, k0)]) = h2;
      *reinterpret_cast<bf16x4*>(&Ws[wswz(n4 + 3, k0)]) = h3;
    }
  }
  __syncthreads();   // the ONLY barrier in the kernel

  // ---- wave decomposition: 8 waves as 2 (M) x 4 (N); each wave owns 64x64
  const int l   = tid & 63;
  const int wid = tid >> 6;
  const int wm  = wid >> 2;          // 0..1
  const int wn  = wid & 3;           // 0..3
  const int lrow = l & 15;
  const int lk   = l >> 4;           // 0..3

  float bv[4];
  #pragma unroll
  for (int fn = 0; fn < 4; ++fn)
    bv[fn] = bias[wn * 64 + fn * 16 + lrow];

  // 4 M-chunks of 128 rows; full K=256 per chunk; no barriers.
  for (int ch = 0; ch < 4; ++ch) {
    const int mb = ch * 128 + wm * 64;
    f32x4 acc[4][4] = {};

    // raw f32 double-buffer for the A fragments (one K-step ahead)
    float4 r0[4], r1[4];
    {
      const float* p0 = xb + (size_t)(mb + lrow) * DIN + lk * 8;
      #pragma unroll
      for (int fm = 0; fm < 4; ++fm) {
        const float* p = p0 + (size_t)fm * 16 * DIN;
        r0[fm] = *reinterpret_cast<const float4*>(p);
        r1[fm] = *reinterpret_cast<const float4*>(p + 4);
      }
    }

    #pragma unroll
    for (int ks = 0; ks < 8; ++ks) {
      bf16x8 a[4];
      #pragma unroll
      for (int fm = 0; fm < 4; ++fm) a[fm] = cvt8(r0[fm], r1[fm]);

      if (ks < 7) {   // issue next K-step's loads before this step's MFMAs
        const float* p0 = xb + (size_t)(mb + lrow) * DIN + (ks + 1) * 32 + lk * 8;
        #pragma unroll
        for (int fm = 0; fm < 4; ++fm) {
          const float* p = p0 + (size_t)fm * 16 * DIN;
          r0[fm] = *reinterpret_cast<const float4*>(p);
          r1[fm] = *reinterpret_cast<const float4*>(p + 4);
        }
      }

      bf16x8 b[4];
      #pragma unroll
      for (int fn = 0; fn < 4; ++fn)
        b[fn] = *reinterpret_cast<const bf16x8*>(
            &Ws[wswz(wn * 64 + fn * 16 + lrow, ks * 32 + lk * 8)]);

      #pragma unroll
      for (int fm = 0; fm < 4; ++fm)
        #pragma unroll
        for (int fn = 0; fn < 4; ++fn)
          acc[fm][fn] = __builtin_amdgcn_mfma_f32_16x16x32_bf16(
              a[fm], b[fn], acc[fm][fn], 0, 0, 0);
    }

    // ---- epilogue for this chunk: add bias, nontemporal f32 stores
    #pragma unroll
    for (int fm = 0; fm < 4; ++fm) {
      const int r0w = mb + fm * 16 + lk * 4;
      #pragma unroll
      for (int fn = 0; fn < 4; ++fn) {
        const int col = wn * 64 + fn * 16 + lrow;
        float* op = ob + (size_t)r0w * DOUT + col;
        #pragma unroll
        for (int rr = 0; rr < 4; ++rr)
          __builtin_nontemporal_store(acc[fm][fn][rr] + bv[fn], op + (size_t)rr * DOUT);
      }
    }
  }
}

extern "C" void kernel_launch(void* const* d_in, const int* in_sizes, int n_in,
                              void* d_out, int out_size, void* d_ws, size_t ws_size,
                              hipStream_t stream) {
  const float* x    = (const float*)d_in[0];
  const int*   idx  = (const int*)d_in[1];
  const float* w    = (const float*)d_in[2];
  const float* bias = (const float*)d_in[3];
  float* out = (float*)d_out;

  adaptive_linear_ws<<<NT, 512, 0, stream>>>(x, idx, w, bias, out);
}